// Round 1
// 232.724 us; speedup vs baseline: 1.0156x; 1.0156x over previous
//
#include <hip/hip_runtime.h>
#include <hip/hip_bf16.h>

// GCN 2-layer + global_add_pool on MI355X.
// R7 changes (latency-targeted, algebraic):
//  - dinv pre-scaling: gemm writes hb[s] = dinv[s]*(x W1)[s]; agg1 writes
//    ob[i] = dinv[i]*o[i]. Aggregation becomes a pure SUM of gathered rows
//    (out_i = dinv_i*(sum + self)) -> per-edge dinv[src] gather and weight
//    FMA deleted (800k dependent 4B gathers per layer gone).
//  - adjacency padded to multiple of 8 with sentinel node N (zero row in
//    hb/ob): row_start 32B-aligned -> srcs loaded as int4 pairs (2 VMEM per
//    8 edges vs 8), no remainder loops, pad gathers hit a hot L1 zero row.
//  - srcs software pipeline: next iteration's int4 pair prefetched during
//    current iteration's gather consume.

typedef _Float16 f16x8 __attribute__((ext_vector_type(8)));
typedef float f32x4 __attribute__((ext_vector_type(4)));

#define BCHUNK 4096

static __device__ __forceinline__ float f16lo(unsigned int u) {
    union { unsigned short s; _Float16 h; } c; c.s = (unsigned short)(u & 0xffff);
    return (float)c.h;
}
static __device__ __forceinline__ float f16hi(unsigned int u) {
    union { unsigned short s; _Float16 h; } c; c.s = (unsigned short)(u >> 16);
    return (float)c.h;
}
static __device__ __forceinline__ unsigned int pack2f16(float x, float y) {
    union { unsigned short s; _Float16 h; } a, b;
    a.h = (_Float16)x; b.h = (_Float16)y;
    return (unsigned int)a.s | ((unsigned int)b.s << 16);
}

// ---------------- bucket binning ----------------

__global__ __launch_bounds__(256) void bin_hist(const int* __restrict__ ei,
                                                int* __restrict__ counts,
                                                int E, int NB, int NBLK) {
    __shared__ int hist[256];
    int t = threadIdx.x, blk = blockIdx.x;
    for (int b = t; b < NB; b += 256) hist[b] = 0;
    __syncthreads();
    int base = blk * BCHUNK;
    int end = min(E, base + BCHUNK);
    for (int e = base + t; e < end; e += 256)
        atomicAdd(&hist[ei[E + e] >> 8], 1);
    __syncthreads();
    for (int b = t; b < NB; b += 256) counts[b * NBLK + blk] = hist[b];
}

__global__ __launch_bounds__(256) void bin_scatter(const int* __restrict__ ei,
                                                   const int* __restrict__ counts,
                                                   unsigned int* __restrict__ bedges,
                                                   int E, int NB, int NBLK) {
    __shared__ int lcur[256];
    int t = threadIdx.x, blk = blockIdx.x;
    for (int b = t; b < NB; b += 256) lcur[b] = counts[b * NBLK + blk];
    __syncthreads();
    int base = blk * BCHUNK;
    int end = min(E, base + BCHUNK);
    for (int e = base + t; e < end; e += 256) {
        int s = ei[e];
        int d = ei[E + e];
        int pos = atomicAdd(&lcur[d >> 8], 1);
        bedges[pos] = (unsigned int)s | ((unsigned int)(d & 255) << 16);
    }
}

// per-bucket degree count via LDS histogram (coalesced cnt write)
__global__ __launch_bounds__(256) void deg_buckets(const unsigned int* __restrict__ bedges,
                                                   const int* __restrict__ counts,
                                                   int* __restrict__ cnt,
                                                   int E, int N, int NB, int NBLK) {
    __shared__ int lcnt[256];
    int b = blockIdx.x, t = threadIdx.x;
    lcnt[t] = 0;
    __syncthreads();
    int bstart = counts[b * NBLK];
    int bend = (b + 1 < NB) ? counts[(b + 1) * NBLK] : E;
    for (int i = bstart + t; i < bend; i += 256)
        atomicAdd(&lcnt[bedges[i] >> 16], 1);
    __syncthreads();
    int node = (b << 8) + t;
    if (node < N) cnt[node] = lcnt[t];
}

// one block per bucket: CSR fill into the bucket's own (L2-local) window.
// R7: also fill the pad region [row_start+c, row_start+cp) with sentinel N.
__global__ __launch_bounds__(256) void fill_buckets(const unsigned int* __restrict__ bedges,
                                                    const int* __restrict__ counts,
                                                    const int* __restrict__ row_start,
                                                    const int* __restrict__ cnt,
                                                    int* __restrict__ srcs,
                                                    int E, int N, int NB, int NBLK) {
    __shared__ int lcur[256];
    int b = blockIdx.x, t = threadIdx.x;
    int node = (b << 8) + t;
    lcur[t] = (node < N) ? row_start[node] : 0;
    __syncthreads();
    int bstart = counts[b * NBLK];
    int bend = (b + 1 < NB) ? counts[(b + 1) * NBLK] : E;
    for (int i = bstart + t; i < bend; i += 256) {
        unsigned int p = bedges[i];
        int pos = atomicAdd(&lcur[p >> 16], 1);
        srcs[pos] = (int)(p & 0xffffu);
    }
    // pad region is disjoint from all scatter writes: no sync needed
    if (node < N) {
        int c = cnt[node];
        int e0 = row_start[node] + c;
        int e1 = row_start[node] + ((c + 7) & ~7);
        for (int j = e0; j < e1; j++) srcs[j] = N;  // sentinel: zero row
    }
}

// ---------------- scans ----------------

__global__ void block_sums(const int* __restrict__ data, int* __restrict__ bsum, int n) {
    __shared__ int s[256];
    int base = blockIdx.x * 1024;
    int t = threadIdx.x;
    int v = 0;
#pragma unroll
    for (int i = 0; i < 4; i++) {
        int idx = base + t * 4 + i;
        if (idx < n) v += data[idx];
    }
    s[t] = v;
    __syncthreads();
    for (int off = 128; off > 0; off >>= 1) {
        if (t < off) s[t] += s[t + off];
        __syncthreads();
    }
    if (t == 0) bsum[blockIdx.x] = s[0];
}

// block sums of PADDED counts (pad8), for the node scan
__global__ void block_sums_pad(const int* __restrict__ data, int* __restrict__ bsum, int n) {
    __shared__ int s[256];
    int base = blockIdx.x * 1024;
    int t = threadIdx.x;
    int v = 0;
#pragma unroll
    for (int i = 0; i < 4; i++) {
        int idx = base + t * 4 + i;
        if (idx < n) v += (data[idx] + 7) & ~7;
    }
    s[t] = v;
    __syncthreads();
    for (int off = 128; off > 0; off >>= 1) {
        if (t < off) s[t] += s[t + off];
        __syncthreads();
    }
    if (t == 0) bsum[blockIdx.x] = s[0];
}

// single-wave exclusive scan over nb (<=64) block sums
__global__ void scan_bsum(int* __restrict__ bsum, int nb) {
    int lane = threadIdx.x & 63;
    int v = (lane < nb) ? bsum[lane] : 0;
    int incl = v;
#pragma unroll
    for (int off = 1; off < 64; off *= 2) {
        int u = __shfl_up(incl, off);
        if (lane >= off) incl += u;
    }
    if (lane < nb) bsum[lane] = incl - v;  // exclusive
}

// generic in-place exclusive scan (given block offsets)
__global__ void scan_apply(int* __restrict__ data, const int* __restrict__ bsum, int n) {
    __shared__ int s[256];
    int base = blockIdx.x * 1024;
    int t = threadIdx.x;
    int loc[4];
    int v = 0;
#pragma unroll
    for (int i = 0; i < 4; i++) {
        int idx = base + t * 4 + i;
        loc[i] = (idx < n) ? data[idx] : 0;
        v += loc[i];
    }
    s[t] = v;
    __syncthreads();
    for (int off = 1; off < 256; off *= 2) {
        int u = (t >= off) ? s[t - off] : 0;
        __syncthreads();
        s[t] += u;
        __syncthreads();
    }
    int excl = s[t] - v + bsum[blockIdx.x];
#pragma unroll
    for (int i = 0; i < 4; i++) {
        int idx = base + t * 4 + i;
        if (idx < n) { data[idx] = excl; excl += loc[i]; }
    }
}

// node scan over PADDED counts: cnt -> row_start (pad8 prefix), dinv (real)
__global__ void scan_nodes(const int* __restrict__ cnt, const int* __restrict__ bsum,
                           int* __restrict__ row_start, float* __restrict__ dinv, int n) {
    __shared__ int s[256];
    int base = blockIdx.x * 1024;
    int t = threadIdx.x;
    int loc[4], pc[4];
    int v = 0;
#pragma unroll
    for (int i = 0; i < 4; i++) {
        int idx = base + t * 4 + i;
        loc[i] = (idx < n) ? cnt[idx] : 0;
        pc[i] = (loc[i] + 7) & ~7;
        v += pc[i];
    }
    s[t] = v;
    __syncthreads();
    for (int off = 1; off < 256; off *= 2) {
        int u = (t >= off) ? s[t - off] : 0;
        __syncthreads();
        s[t] += u;
        __syncthreads();
    }
    int excl = s[t] - v + bsum[blockIdx.x];
#pragma unroll
    for (int i = 0; i < 4; i++) {
        int idx = base + t * 4 + i;
        if (idx < n) {
            row_start[idx] = excl;
            dinv[idx] = rsqrtf((float)loc[i] + 1.0f);
            excl += pc[i];
        }
    }
}

// ---------------- W fragment prep ----------------
__global__ void wprep(const float* __restrict__ W, _Float16* __restrict__ wfrag) {
    int idx = blockIdx.x * 256 + threadIdx.x;  // 2048 total
    if (idx >= 2048) return;
    int lane = idx & 63;
    int kc = (idx >> 6) & 3;
    int nb = idx >> 8;
    int col = nb * 16 + (lane & 15);
    int krow = kc * 32 + (lane >> 4) * 8;
#pragma unroll
    for (int j = 0; j < 8; j++)
        wfrag[idx * 8 + j] = (_Float16)W[(krow + j) * 128 + col];
}

// ---------------- GEMM: C[M x 128] = dinv[row] * (A[M x 128] @ W), fp16 MFMA ----------------
__global__ __launch_bounds__(256) void gemm_mfma_f32in(const float* __restrict__ A,
                                                       const _Float16* __restrict__ wfrag,
                                                       const float* __restrict__ dinv,
                                                       _Float16* __restrict__ C, int M) {
    __shared__ _Float16 As[128 * 136];
    int t = threadIdx.x;
    int row0 = blockIdx.x * 128;

    const float4* A4 = (const float4*)A;
#pragma unroll
    for (int it = 0; it < 16; it++) {
        int v = it * 256 + t;
        int row = v >> 5;
        int seg = v & 31;
        float4 val = make_float4(0.f, 0.f, 0.f, 0.f);
        if (row0 + row < M) val = A4[(size_t)(row0 + row) * 32 + seg];
        _Float16* p = &As[row * 136 + seg * 4];
        p[0] = (_Float16)val.x; p[1] = (_Float16)val.y;
        p[2] = (_Float16)val.z; p[3] = (_Float16)val.w;
    }
    __syncthreads();

    int wv = t >> 6;
    int lane = t & 63;
    int lrow = lane & 15;
    int lq = lane >> 4;

    f32x4 acc[2][8];
#pragma unroll
    for (int i = 0; i < 2; i++)
#pragma unroll
        for (int j = 0; j < 8; j++) acc[i][j] = (f32x4){0.f, 0.f, 0.f, 0.f};

#pragma unroll
    for (int kc = 0; kc < 4; kc++) {
        int k0 = kc * 32;
        f16x8 a0 = *((const f16x8*)&As[(wv * 32 + lrow) * 136 + k0 + lq * 8]);
        f16x8 a1 = *((const f16x8*)&As[(wv * 32 + 16 + lrow) * 136 + k0 + lq * 8]);
#pragma unroll
        for (int nb = 0; nb < 8; nb++) {
            f16x8 b = ((const f16x8*)wfrag)[(nb * 4 + kc) * 64 + lane];
            acc[0][nb] = __builtin_amdgcn_mfma_f32_16x16x32_f16(a0, b, acc[0][nb], 0, 0, 0);
            acc[1][nb] = __builtin_amdgcn_mfma_f32_16x16x32_f16(a1, b, acc[1][nb], 0, 0, 0);
        }
    }

    // C/D layout: col = lane&15, row = (lane>>4)*4 + reg
#pragma unroll
    for (int ti = 0; ti < 2; ti++) {
#pragma unroll
        for (int r = 0; r < 4; r++) {
            int row = row0 + wv * 32 + ti * 16 + lq * 4 + r;
            if (row < M) {
                float dv = dinv[row];
#pragma unroll
                for (int nb = 0; nb < 8; nb++)
                    C[(size_t)row * 128 + nb * 16 + lrow] = (_Float16)(acc[ti][nb][r] * dv);
            }
        }
    }
}

// ---------------- agg1: o = relu(dn*(sum + self) + b1); ob = dn*o ----------------
// hb rows are pre-scaled by dinv[src]; inner loop is a pure sum of gathered
// rows. Adjacency padded to mult-of-8 with sentinel zero row N.
__global__ __launch_bounds__(256) void agg1(const _Float16* __restrict__ hb,
                                            const int* __restrict__ srcs,
                                            const int* __restrict__ row_start,
                                            const int* __restrict__ cnt,
                                            const float* __restrict__ dinv,
                                            const float* __restrict__ bias,
                                            _Float16* __restrict__ ob, int n) {
    int node = blockIdx.x * 4 + (threadIdx.x >> 6);
    if (node >= n) return;
    int lane = threadIdx.x & 63;
    int s0 = row_start[node];
    int c = cnt[node];
    int nit = (c + 7) >> 3;
    float dn = dinv[node];
    const unsigned int* h2 = (const unsigned int*)hb;
    unsigned int hs = h2[(size_t)node * 64 + lane];           // self (pre-scaled)
    float2 bv = ((const float2*)bias)[lane];
    float ax = 0.f, ay = 0.f, bx = 0.f, by = 0.f;
    const int4* sp = (const int4*)(srcs + s0);
    int4 sa = {}, sb = {};
    if (nit > 0) { sa = sp[0]; sb = sp[1]; }
    for (int it = 0; it < nit; it++) {
        int4 ca = sa, cb = sb;
        int nx = (it + 1 < nit) ? it + 1 : it;   // branchless src prefetch
        sa = sp[nx * 2]; sb = sp[nx * 2 + 1];
        unsigned int v0 = h2[(size_t)(unsigned)ca.x * 64 + lane];
        unsigned int v1 = h2[(size_t)(unsigned)ca.y * 64 + lane];
        unsigned int v2 = h2[(size_t)(unsigned)ca.z * 64 + lane];
        unsigned int v3 = h2[(size_t)(unsigned)ca.w * 64 + lane];
        unsigned int v4 = h2[(size_t)(unsigned)cb.x * 64 + lane];
        unsigned int v5 = h2[(size_t)(unsigned)cb.y * 64 + lane];
        unsigned int v6 = h2[(size_t)(unsigned)cb.z * 64 + lane];
        unsigned int v7 = h2[(size_t)(unsigned)cb.w * 64 + lane];
        ax += f16lo(v0); ay += f16hi(v0);
        bx += f16lo(v1); by += f16hi(v1);
        ax += f16lo(v2); ay += f16hi(v2);
        bx += f16lo(v3); by += f16hi(v3);
        ax += f16lo(v4); ay += f16hi(v4);
        bx += f16lo(v5); by += f16hi(v5);
        ax += f16lo(v6); ay += f16hi(v6);
        bx += f16lo(v7); by += f16hi(v7);
    }
    ax += bx + f16lo(hs);
    ay += by + f16hi(hs);
    float ox = fmaxf(fmaf(dn, ax, bv.x), 0.f) * dn;  // relu(dn*sum+b1), pre-scale for L2
    float oy = fmaxf(fmaf(dn, ay, bv.y), 0.f) * dn;
    ((unsigned int*)ob)[(size_t)node * 64 + lane] = pack2f16(ox, oy);
}

// ---------------- agg2 + pool: P[g] += t_i = dn*(sum + self) ----------------
__global__ __launch_bounds__(256) void agg2_pool(const _Float16* __restrict__ ob,
                                                 const int* __restrict__ srcs,
                                                 const int* __restrict__ row_start,
                                                 const int* __restrict__ cnt,
                                                 const float* __restrict__ dinv,
                                                 const int* __restrict__ batch,
                                                 float* __restrict__ P, int n) {
    __shared__ float red[4][128];
    int wv = threadIdx.x >> 6;
    int lane = threadIdx.x & 63;
    int base = blockIdx.x * 4;
    int node = base + wv;
    const unsigned int* h2 = (const unsigned int*)ob;
    float tx = 0.f, ty = 0.f;
    int g = -1;
    if (node < n) {
        g = batch[node];
        int s0 = row_start[node];
        int c = cnt[node];
        int nit = (c + 7) >> 3;
        float dn = dinv[node];
        unsigned int hs = h2[(size_t)node * 64 + lane];
        float ax = 0.f, ay = 0.f, bx = 0.f, by = 0.f;
        const int4* sp = (const int4*)(srcs + s0);
        int4 sa = {}, sb = {};
        if (nit > 0) { sa = sp[0]; sb = sp[1]; }
        for (int it = 0; it < nit; it++) {
            int4 ca = sa, cb = sb;
            int nx = (it + 1 < nit) ? it + 1 : it;
            sa = sp[nx * 2]; sb = sp[nx * 2 + 1];
            unsigned int v0 = h2[(size_t)(unsigned)ca.x * 64 + lane];
            unsigned int v1 = h2[(size_t)(unsigned)ca.y * 64 + lane];
            unsigned int v2 = h2[(size_t)(unsigned)ca.z * 64 + lane];
            unsigned int v3 = h2[(size_t)(unsigned)ca.w * 64 + lane];
            unsigned int v4 = h2[(size_t)(unsigned)cb.x * 64 + lane];
            unsigned int v5 = h2[(size_t)(unsigned)cb.y * 64 + lane];
            unsigned int v6 = h2[(size_t)(unsigned)cb.z * 64 + lane];
            unsigned int v7 = h2[(size_t)(unsigned)cb.w * 64 + lane];
            ax += f16lo(v0); ay += f16hi(v0);
            bx += f16lo(v1); by += f16hi(v1);
            ax += f16lo(v2); ay += f16hi(v2);
            bx += f16lo(v3); by += f16hi(v3);
            ax += f16lo(v4); ay += f16hi(v4);
            bx += f16lo(v5); by += f16hi(v5);
            ax += f16lo(v6); ay += f16hi(v6);
            bx += f16lo(v7); by += f16hi(v7);
        }
        ax += bx + f16lo(hs);
        ay += by + f16hi(hs);
        tx = dn * ax;
        ty = dn * ay;
    }
    // pool: check if block's 4 nodes share one graph
    int lastn = min(base + 3, n - 1);
    bool uniform = (base < n) && (batch[base] == batch[lastn]) && (base + 3 < n);
    if (uniform) {
        red[wv][lane * 2 + 0] = tx;
        red[wv][lane * 2 + 1] = ty;
        __syncthreads();
        if (wv == 0) {
            float sx = red[0][lane * 2] + red[1][lane * 2] + red[2][lane * 2] + red[3][lane * 2];
            float sy = red[0][lane * 2 + 1] + red[1][lane * 2 + 1] + red[2][lane * 2 + 1] + red[3][lane * 2 + 1];
            atomicAdd(&P[g * 128 + lane * 2 + 0], sx);
            atomicAdd(&P[g * 128 + lane * 2 + 1], sy);
        }
    } else if (node < n) {
        atomicAdd(&P[g * 128 + lane * 2 + 0], tx);
        atomicAdd(&P[g * 128 + lane * 2 + 1], ty);
    }
}

// ---------------- out = P @ W2 + n_g * b2, one block per graph ----------------
__global__ __launch_bounds__(128) void gemm_small(const float* __restrict__ P,
                                                  const float* __restrict__ W2,
                                                  const float* __restrict__ b2,
                                                  const int* __restrict__ batch,
                                                  float* __restrict__ out, int n) {
    __shared__ float prow[128];
    int g = blockIdx.x;
    int c = threadIdx.x;
    prow[c] = P[g * 128 + c];
    __syncthreads();
    // n_g via binary search over sorted batch
    int lo = 0, hi = n;
    while (lo < hi) { int mid = (lo + hi) >> 1; if (batch[mid] < g) lo = mid + 1; else hi = mid; }
    int start = lo;
    hi = n;
    while (lo < hi) { int mid = (lo + hi) >> 1; if (batch[mid] < g + 1) lo = mid + 1; else hi = mid; }
    float ng = (float)(lo - start);
    float acc = 0.f;
#pragma unroll 8
    for (int k = 0; k < 128; k++) acc = fmaf(prow[k], W2[k * 128 + c], acc);
    out[g * 128 + c] = acc + ng * b2[c];
}

extern "C" void kernel_launch(void* const* d_in, const int* in_sizes, int n_in,
                              void* d_out, int out_size, void* d_ws, size_t ws_size,
                              hipStream_t stream) {
    const float* x  = (const float*)d_in[0];
    const int*   ei = (const int*)d_in[1];
    const int*   batch = (const int*)d_in[2];
    const float* W1 = (const float*)d_in[3];
    const float* b1 = (const float*)d_in[4];
    const float* W2 = (const float*)d_in[5];
    const float* b2 = (const float*)d_in[6];
    float* out = (float*)d_out;

    const int N = in_sizes[2];       // 50000 (assumed <= 65536)
    const int E = in_sizes[1] / 2;   // 800000

    const int NB = (N + 255) >> 8;              // 196 buckets
    const int NBLK = (E + BCHUNK - 1) / BCHUNK; // 196 chunks
    const int ncounts = NB * NBLK;              // 38416
    const int SRP = E + 7 * N + 16;             // padded srcs capacity (pad8)

    // workspace layout (hb/ob have N+8 rows; row N is the sentinel zero row)
    _Float16* hb = (_Float16*)d_ws;                  // (N+8)*128 halves
    _Float16* ob = hb + (size_t)(N + 8) * 128;       // (N+8)*128 halves
    int* cnt  = (int*)(ob + (size_t)(N + 8) * 128);  // N
    int* row_start = cnt + N;                        // N
    float* dinv    = (float*)(row_start + N);        // N
    int* srcs      = (int*)(dinv + N);               // SRP
    unsigned int* bedges = (unsigned int*)(srcs + SRP); // E
    int* counts    = (int*)(bedges + E);             // NB*NBLK
    _Float16* wfrag1 = (_Float16*)(counts + ncounts);// 128*128
    float* P       = (float*)(wfrag1 + 128 * 128);   // 128*128 f32
    int* bsum      = (int*)(P + 128 * 128);          // <=64

    const int nbc = (ncounts + 1023) / 1024;  // <=64
    const int nbn = (N + 1023) / 1024;        // <=64

    hipMemsetAsync(P, 0, 128 * 128 * sizeof(float), stream);
    hipMemsetAsync(hb + (size_t)N * 128, 0, 128 * sizeof(_Float16), stream);
    hipMemsetAsync(ob + (size_t)N * 128, 0, 128 * sizeof(_Float16), stream);
    wprep<<<8, 256, 0, stream>>>(W1, wfrag1);

    // --- bucket binning + CSR build (padded to mult-of-8 per node) ---
    bin_hist<<<NBLK, 256, 0, stream>>>(ei, counts, E, NB, NBLK);
    block_sums<<<nbc, 256, 0, stream>>>(counts, bsum, ncounts);
    scan_bsum<<<1, 64, 0, stream>>>(bsum, nbc);
    scan_apply<<<nbc, 256, 0, stream>>>(counts, bsum, ncounts);
    bin_scatter<<<NBLK, 256, 0, stream>>>(ei, counts, bedges, E, NB, NBLK);
    deg_buckets<<<NB, 256, 0, stream>>>(bedges, counts, cnt, E, N, NB, NBLK);
    block_sums_pad<<<nbn, 256, 0, stream>>>(cnt, bsum, N);
    scan_bsum<<<1, 64, 0, stream>>>(bsum, nbn);
    scan_nodes<<<nbn, 256, 0, stream>>>(cnt, bsum, row_start, dinv, N);
    fill_buckets<<<NB, 256, 0, stream>>>(bedges, counts, row_start, cnt, srcs, E, N, NB, NBLK);

    const int gemm_grid = (N + 127) / 128;

    // layer 1: hb = dinv*(x@W1) ; ob = dinv*relu(dn*(sum+self) + b1)
    gemm_mfma_f32in<<<gemm_grid, 256, 0, stream>>>(x, wfrag1, dinv, hb, N);
    agg1<<<(N + 3) / 4, 256, 0, stream>>>(hb, srcs, row_start, cnt, dinv, b1, ob, N);
    // layer 2 (reordered): P = pool(Â o) ; out = P@W2 + n_g*b2
    agg2_pool<<<(N + 3) / 4, 256, 0, stream>>>(ob, srcs, row_start, cnt, dinv, batch, P, N);
    gemm_small<<<128, 128, 0, stream>>>(P, W2, b2, batch, out, N);
}